// Round 11
// baseline (225.979 us; speedup 1.0000x reference)
//
#include <hip/hip_runtime.h>

#define NN    4096
#define NE    5
#define NC    2
#define FINF  128
#define FOUTF 64
#define CAP   384

// ---------------- workspace layout (bytes) ----------------
// cnt   @ 0        : 16384
// epack @ 16384    : NN*CAP*16 = 25165824   (int4: u, wA pair, wB pair, wC pair; fp16)
// DdA   @ 25182208 : 32768
// Dd1   @ 25214976 : 32768
// hh    @ 25247744 : NN*FINF*2 = 1048576    (fp16 h panel)
// XhA   @ 26296320 : NC*NN*FINF*2 = 2097152
// Xh1   @ 28393472 : 2097152
// end ~ 30.5 MB

union f16u { unsigned short s; _Float16 h; };

static __device__ __forceinline__ unsigned short f2h(float x)
{
    f16u u; u.h = (_Float16)x; return u.s;
}
static __device__ __forceinline__ float lo16f(unsigned x)
{
    f16u u; u.s = (unsigned short)(x & 0xffff); return (float)u.h;
}
static __device__ __forceinline__ float hi16f(unsigned x)
{
    f16u u; u.s = (unsigned short)(x >> 16); return (float)u.h;
}
static __device__ __forceinline__ unsigned pack2h(float a, float b)
{
    return (unsigned)f2h(a) | ((unsigned)f2h(b) << 16);
}

// blocks 0..3: zero cnt; blocks 4..515: f32 h -> fp16 hh
__global__ __launch_bounds__(256) void init_misc(int4* __restrict__ cnt4,
                                                 const float4* __restrict__ h4,
                                                 uint2* __restrict__ hh)
{
    int b = blockIdx.x;
    if (b < 4) {
        cnt4[b * 256 + threadIdx.x] = int4{0, 0, 0, 0};
    } else {
        int i = (b - 4) * 256 + threadIdx.x;        // 131072 float4s
        float4 f = h4[i];
        uint2 r;
        r.x = pack2h(f.x, f.y);
        r.y = pack2h(f.z, f.w);
        hh[i] = r;
    }
}

// Coalesced float4 streaming reads of A (5 slices), global-atomic append,
// ONE 16-byte packed store per edge.
__global__ __launch_bounds__(256) void build_csc(
    const float* __restrict__ A,
    const float* __restrict__ W1_0,
    const float* __restrict__ W2_0,
    const float* __restrict__ W1_1,
    int*  __restrict__ cnt,
    int4* __restrict__ epack)
{
    float fA0[NE], fA1[NE], fB0[NE], fB1[NE], fC0[NE], fC1[NE];
#pragma unroll
    for (int e = 0; e < NE; ++e) {
        fA0[e] = W1_0[e];      fA1[e] = W1_0[NE + e];
        fB0[e] = W2_0[e];      fB1[e] = W2_0[NE + e];
        fC0[e] = W1_1[e];      fC1[e] = W1_1[NE + e];
    }

    const size_t S = (size_t)NN * NN / 4;   // float4 per e-slice
    const float4* A4 = (const float4*)A;
    size_t stride = (size_t)gridDim.x * blockDim.x;
    for (size_t i = (size_t)blockIdx.x * blockDim.x + threadIdx.x; i < S; i += stride) {
        float4 q0 = A4[i];
        float4 q1 = A4[i + S];
        float4 q2 = A4[i + 2 * S];
        float4 q3 = A4[i + 3 * S];
        float4 q4 = A4[i + 4 * S];
        int u  = (int)(i >> 10);            // 1024 float4 per row
        int v0 = ((int)i & 1023) << 2;
#define DO_COMP(comp, joff)                                                      \
        {                                                                        \
            float a0 = q0.comp, a1 = q1.comp, a2 = q2.comp,                      \
                  a3 = q3.comp, a4 = q4.comp;                                    \
            if (a0 != 0.f || a1 != 0.f || a2 != 0.f || a3 != 0.f || a4 != 0.f) { \
                float sA0 = fA0[0]*a0 + fA0[1]*a1 + fA0[2]*a2 + fA0[3]*a3 + fA0[4]*a4; \
                float sA1 = fA1[0]*a0 + fA1[1]*a1 + fA1[2]*a2 + fA1[3]*a3 + fA1[4]*a4; \
                float sB0 = fB0[0]*a0 + fB0[1]*a1 + fB0[2]*a2 + fB0[3]*a3 + fB0[4]*a4; \
                float sB1 = fB1[0]*a0 + fB1[1]*a1 + fB1[2]*a2 + fB1[3]*a3 + fB1[4]*a4; \
                float sC0 = fC0[0]*a0 + fC0[1]*a1 + fC0[2]*a2 + fC0[3]*a3 + fC0[4]*a4; \
                float sC1 = fC1[0]*a0 + fC1[1]*a1 + fC1[2]*a2 + fC1[3]*a3 + fC1[4]*a4; \
                int v = v0 + joff;                                               \
                int pos = atomicAdd(&cnt[v], 1);                                 \
                if (pos < CAP) {                                                 \
                    int4 rec;                                                    \
                    rec.x = u;                                                   \
                    rec.y = (int)pack2h(__expf(sA0), __expf(sA1));               \
                    rec.z = (int)pack2h(__expf(sB0), __expf(sB1));               \
                    rec.w = (int)pack2h(sC0, sC1);                               \
                    epack[v * CAP + pos] = rec;                                  \
                }                                                                \
            }                                                                    \
        }
        DO_COMP(x, 0)
        DO_COMP(y, 1)
        DO_COMP(z, 2)
        DO_COMP(w, 3)
#undef DO_COMP
    }
}

// One workgroup (256 threads) per (column v, channel c); c = blockIdx&1 so
// consecutive blocks (round-robin across XCDs) pin each channel's 2MB panel
// to half the XCDs -> gathers stay L2-resident.
// Phase 1: stage edges {u, w_c} into LDS, reduce weight-sum + denominator.
// Phase 2: 8 edge-groups x 32 lanes, uint2 (4 x fp16) row gathers, LDS partials.
// Phase 3: tree-reduce -> y row (normalized), write fp16 panel + denom.
// Phase 4: 4-way feature-split 128x64 matvec, LDS combine, bias, relu -> out.
template<int STAGE>
__global__ __launch_bounds__(256) void spmm_col(
    const int*   __restrict__ cnt,
    const int4*  __restrict__ epack,
    const unsigned short* __restrict__ Xh_in, // stage0: [NN][128]; else [NC][NN][128]
    const float* __restrict__ Dd_in,    // stages 1/2: [NC][NN]
    const float* __restrict__ gW,       // [NC][FINF][FOUTF]
    const float* __restrict__ gb,       // [NC][FOUTF]
    float*       __restrict__ out,      // [NC][3][NN][FOUTF]
    unsigned short* __restrict__ Xh_out,// stages 0/1
    float*       __restrict__ Dd_out)   // stages 0/1
{
    int c = blockIdx.x & 1;
    int v = blockIdx.x >> 1;
    int n = cnt[v];
    if (n > CAP) n = CAP;

    __shared__ float2 s_e[CAP];          // {u bits, w}
    __shared__ float  s_red[2];          // sum, d
    __shared__ float4 s_acc[8][32];      // 4 KB partials
    __shared__ float  s_y[FINF];
    __shared__ float  s_part[4][FOUTF];
    __shared__ float  s_inv;

    int tid = threadIdx.x;
    if (tid < 2) s_red[tid] = 0.f;
    __syncthreads();

    float l = 0.f, ld = 0.f;
    for (int i = tid; i < n; i += 256) {
        int4 E = epack[v * CAP + i];
        unsigned wb = (unsigned)((STAGE == 0) ? E.y : (STAGE == 1) ? E.z : E.w);
        float w = c ? hi16f(wb) : lo16f(wb);
        s_e[i] = float2{__int_as_float(E.x), w};
        l += w;
        if (STAGE != 0) ld += w * Dd_in[c * NN + E.x];
    }
    if (STAGE == 0) ld = l;

#pragma unroll
    for (int m = 32; m >= 1; m >>= 1) {
        l  += __shfl_xor(l,  m);
        ld += __shfl_xor(ld, m);
    }
    if ((tid & 63) == 0) {
        atomicAdd(&s_red[0], l);
        atomicAdd(&s_red[1], ld);
    }
    __syncthreads();

    int grp = tid >> 5, lane = tid & 31;
    float4 a = {0.f, 0.f, 0.f, 0.f};

    {
        const uint2* P = (const uint2*)Xh_in;
        if (STAGE != 0) P += (size_t)c * NN * 32;   // per-channel panel
#pragma unroll 2
        for (int i = grp; i < n; i += 8) {
            float2 e = s_e[i];
            uint2 b = P[(size_t)__float_as_int(e.x) * 32 + lane];
            a.x += e.y * lo16f(b.x);
            a.y += e.y * hi16f(b.x);
            a.z += e.y * lo16f(b.y);
            a.w += e.y * hi16f(b.y);
        }
    }

    s_acc[grp][lane] = a;
    __syncthreads();

    // Phase 3: 128 threads reduce over 8 groups
    if (tid < FINF) {
        int f = tid;
        const float* base = (const float*)s_acc;     // [8][128]
        float s = 0.f;
#pragma unroll
        for (int g = 0; g < 8; ++g) s += base[g * 128 + f];

        float inv = 1.f;
        if (STAGE < 2 && n > 0) inv = 1.f / s_red[0];
        float val = s * inv;

        s_y[f] = val;
        if (STAGE < 2)
            Xh_out[((size_t)c * NN + v) * FINF + f] = f2h(val);
        if (f == 0) {
            float dvn = s_red[1] * inv;
            s_inv = (dvn != 0.f) ? (1.f / dvn) : 1.f;
            if (STAGE < 2) Dd_out[c * NN + v] = dvn;
        }
    }
    __syncthreads();

    // Phase 4: all 256 threads; part p covers features p*32..p*32+31
    {
        int p = tid >> 6, o = tid & 63;
        const float* y = s_y + p * 32;
        const float* w = gW + (size_t)c * FINF * FOUTF + (size_t)p * 32 * FOUTF + o;
        float acc = 0.f;
#pragma unroll 8
        for (int f2 = 0; f2 < 32; ++f2)
            acc += y[f2] * w[(size_t)f2 * FOUTF];
        s_part[p][o] = acc;
    }
    __syncthreads();
    if (tid < FOUTF) {
        int o = tid;
        float acc = s_part[0][o] + s_part[1][o] + s_part[2][o] + s_part[3][o];
        float r = acc * s_inv + gb[c * FOUTF + o];
        out[(((size_t)c * 3 + STAGE) * NN + v) * FOUTF + o] = fmaxf(r, 0.f);
    }
}

extern "C" void kernel_launch(void* const* d_in, const int* in_sizes, int n_in,
                              void* d_out, int out_size, void* d_ws, size_t ws_size,
                              hipStream_t stream)
{
    const float* A     = (const float*)d_in[0];
    const float* h     = (const float*)d_in[1];
    const float* W1_0  = (const float*)d_in[2];
    const float* W2_0  = (const float*)d_in[3];
    const float* W1_1  = (const float*)d_in[4];
    const float* gW    = (const float*)d_in[5];
    const float* gb    = (const float*)d_in[6];
    float* out = (float*)d_out;

    char* ws = (char*)d_ws;
    int*            cnt   = (int*)(ws);
    int4*           epack = (int4*)(ws + 16384);
    float*          DdA   = (float*)(ws + 25182208);
    float*          Dd1   = (float*)(ws + 25214976);
    uint2*          hh    = (uint2*)(ws + 25247744);
    unsigned short* XhA   = (unsigned short*)(ws + 26296320);
    unsigned short* Xh1   = (unsigned short*)(ws + 28393472);

    init_misc<<<516, 256, 0, stream>>>((int4*)cnt, (const float4*)h, hh);
    build_csc<<<2048, 256, 0, stream>>>(A, W1_0, W2_0, W1_1, cnt, epack);

    // Stage A: softmax wA, gather fp16 hh -> out[:,0], XhA, DdA
    spmm_col<0><<<NN * NC, 256, 0, stream>>>(cnt, epack, (const unsigned short*)hh, nullptr, gW, gb, out, XhA, DdA);
    // Stage B: softmax wB, gather XhA     -> out[:,1], Xh1, Dd1
    spmm_col<1><<<NN * NC, 256, 0, stream>>>(cnt, epack, XhA, DdA, gW, gb, out, Xh1, Dd1);
    // Stage C: raw wC, gather Xh1         -> out[:,2]
    spmm_col<2><<<NN * NC, 256, 0, stream>>>(cnt, epack, Xh1, Dd1, gW, gb, out, nullptr, nullptr);
}